// Round 4
// baseline (1021.888 us; speedup 1.0000x reference)
//
#include <hip/hip_runtime.h>
#include <hip/hip_bf16.h>
#include <stdint.h>

#define LOG2E 1.44269504088896340736f
#define LN2   0.69314718055994530942f

typedef __attribute__((ext_vector_type(8))) __bf16 bf16x8;
typedef __attribute__((ext_vector_type(4))) float  f32x4;

static constexpr int B = 128, S = 512, T = 256;
static constexpr int LDP = T + 8;   // padded LDS row (bf16 elems)

static __device__ __forceinline__ uint pack_bf16x2(float a, float b) {
    __hip_bfloat162 h = __float22bfloat162_rn(make_float2(a, b));
    union { __hip_bfloat162 h; uint u; } cv; cv.h = h;
    return cv.u;
}
static __device__ __forceinline__ ushort f2bf(float f) {
    uint u = __float_as_uint(f);
    return (ushort)((u + 0x7FFFu + ((u >> 16) & 1u)) >> 16);  // RTNE
}
static __device__ __forceinline__ float bf2f(ushort u) {
    return __uint_as_float(((uint)u) << 16);
}

// ---------------- prep: emx = bf16( exp(em) ), elementwise over B*S*T ----------------
__global__ void prep_emx(const float* __restrict__ em, ushort* __restrict__ emx) {
    size_t i4 = ((size_t)blockIdx.x * blockDim.x + threadIdx.x) * 4;
    f32x4 e = *reinterpret_cast<const f32x4*>(&em[i4]);
    uint2 w;
    w.x = pack_bf16x2(exp2f(e[0] * LOG2E), exp2f(e[1] * LOG2E));
    w.y = pack_bf16x2(exp2f(e[2] * LOG2E), exp2f(e[3] * LOG2E));
    *reinterpret_cast<uint2*>(&emx[i4]) = w;
}

// ---------------- main scan ----------------
// 2 independent 16-batch chains per WG (512 thr, 8 waves = 2 waves/SIMD, one per
// chain) so each SIMD always has a second chain to issue while the first stalls.
// Renormalization every 4 steps (delayed, exact power-of-2): worst-case growth
// <= 2^23/step -> <= 2^91 over a group, safe in bf16/fp32. Mask-generic via
// per-lane pending-scale + running vmax. Both scans instruction-identical when
// mask==1 -> bitwise-identical results -> partition - score == 0 exactly.
template<bool PRE>
__launch_bounds__(512, 2)
__global__ void crf_scan(const float* __restrict__ em,      // [B][S][T] fp32
                         const ushort* __restrict__ emx,    // [B][S][T] bf16 exp(em) (PRE)
                         const int* __restrict__ mask,      // [B][S] int32
                         const float* __restrict__ startt,  // [T]
                         const float* __restrict__ endt,    // [T]
                         const float* __restrict__ trans,   // [T][T] fp32
                         float* __restrict__ res)           // [2][B] log2-domain results
{
    const int tid  = threadIdx.x;
    const int wave = tid >> 6;
    const int c    = wave >> 2;         // chain 0/1 within WG
    const int jq   = wave & 3;          // j quarter: [64*jq, 64*jq+64)
    const int lane = tid & 63;
    const int q    = lane >> 4;         // quad 0..3
    const int l    = lane & 15;         // local batch 0..15
    const int scan = blockIdx.x & 1;
    const int bg   = blockIdx.x >> 1;   // 0..3
    const int b    = bg * 32 + c * 16 + l;

    __shared__ __align__(16) ushort Al[2][2][16][LDP];   // [dbuf][chain][batch][state]
    __shared__ float mxbuf[2][4][16];                    // [chain][jq][batch]

    // ---- Build Et fragments in-register from trans (A-operand, step-invariant).
    // A[m = lane&15 -> state j][k = quad*8+jj -> i]; Et[j][i] = exp(trans[i][j]).
    bf16x8 Afr[4][8];
    #pragma unroll
    for (int mt = 0; mt < 4; ++mt) {
        int j = jq * 64 + mt * 16 + l;
        #pragma unroll
        for (int kt = 0; kt < 8; ++kt) {
            union { bf16x8 v; ushort u[8]; } fr;
            #pragma unroll
            for (int jj = 0; jj < 8; ++jj) {
                int i = kt * 32 + q * 8 + jj;
                fr.u[jj] = f2bf(exp2f(trans[i * T + j] * LOG2E));
            }
            Afr[mt][kt] = fr.v;
        }
    }

    const float*  emrow = em  + (size_t)b * S * T;
    const ushort* exrow = PRE ? emx + (size_t)b * S * T : nullptr;
    const int*    mrow  = mask + (size_t)b * S;

    int ls = 0;
    int buf = 0;

    // ---- init: alpha0 = exp(start + em[:,0]), normalized once
    {
        float v0[4][4]; float mx = 0.0f;
        #pragma unroll
        for (int t = 0; t < 4; ++t) {
            int j0 = jq * 64 + t * 16 + q * 4;
            f32x4 e4 = *reinterpret_cast<const f32x4*>(&emrow[j0]);
            f32x4 s4 = *reinterpret_cast<const f32x4*>(&startt[j0]);
            #pragma unroll
            for (int r = 0; r < 4; ++r) {
                v0[t][r] = exp2f((e4[r] + s4[r]) * LOG2E);
                mx = fmaxf(mx, v0[t][r]);
            }
        }
        mx = fmaxf(mx, __shfl_xor(mx, 16));
        mx = fmaxf(mx, __shfl_xor(mx, 32));
        if (q == 0) mxbuf[c][jq][l] = mx;
        __syncthreads();
        float gmx = fmaxf(fmaxf(mxbuf[c][0][l], mxbuf[c][1][l]),
                          fmaxf(mxbuf[c][2][l], mxbuf[c][3][l]));
        int e = (int)((__float_as_uint(gmx) >> 23) & 255u) - 127;
        float sc = __uint_as_float((uint)(127 - e) << 23);   // exact 2^-e
        ls = e;
        #pragma unroll
        for (int t = 0; t < 4; ++t) {
            int j0 = jq * 64 + t * 16 + q * 4;
            uint2 w;
            w.x = pack_bf16x2(v0[t][0] * sc, v0[t][1] * sc);
            w.y = pack_bf16x2(v0[t][2] * sc, v0[t][3] * sc);
            *reinterpret_cast<uint2*>(&Al[0][c][l][j0]) = w;
        }
        __syncthreads();                       // mxbuf consumed by all waves
        if (q == 0) mxbuf[c][jq][l] = mx * sc; // max of stored alpha0
        __syncthreads();
    }

    // ---- prefetch step s=1
    uint2 exv[4]; f32x4 emv[4];
    #pragma unroll
    for (int t = 0; t < 4; ++t) {
        int j0 = jq * 64 + t * 16 + q * 4;
        if (PRE) exv[t] = *reinterpret_cast<const uint2*>(&exrow[(size_t)T + j0]);
        else     emv[t] = *reinterpret_cast<const f32x4*>(&emrow[(size_t)T + j0]);
    }
    int mkv = scan ? mrow[1] : 1;

    for (int g = 0; g < 128; ++g) {
        const int s0 = 1 + g * 4;

        // group start: kappa from stored-alpha max (written at last group's end)
        float gmx = fmaxf(fmaxf(mxbuf[c][0][l], mxbuf[c][1][l]),
                          fmaxf(mxbuf[c][2][l], mxbuf[c][3][l]));
        int   kap  = (int)((__float_as_uint(gmx) >> 23) & 255u) - 127;
        float pend = __uint_as_float((uint)(127 - kap) << 23);   // exact 2^-kap
        int   pk   = kap;
        float vml  = gmx;   // running max of stored alpha (for next kappa)

        #pragma unroll
        for (int u = 0; u < 4; ++u) {
            const int s = s0 + u;
            if (s >= S) break;
            const bool rn = (u == 3) || (s == S - 1);
            const int  nb = buf ^ 1;

            // prefetch next step's em (+mask)
            uint2 exn[4]; f32x4 emn[4];
            if (s + 1 < S) {
                #pragma unroll
                for (int t = 0; t < 4; ++t) {
                    int j0 = jq * 64 + t * 16 + q * 4;
                    if (PRE) exn[t] = *reinterpret_cast<const uint2*>(&exrow[(size_t)(s + 1) * T + j0]);
                    else     emn[t] = *reinterpret_cast<const f32x4*>(&emrow[(size_t)(s + 1) * T + j0]);
                }
            }
            const int mkn = (scan && s + 1 < S) ? mrow[s + 1] : 1;

            // MFMA: P[j][b] = sum_i Et[j][i] * alpha_stored[b][i]
            f32x4 acc[4] = {f32x4{0,0,0,0}, f32x4{0,0,0,0}, f32x4{0,0,0,0}, f32x4{0,0,0,0}};
            #pragma unroll
            for (int kt = 0; kt < 8; ++kt) {
                bf16x8 bfr = *reinterpret_cast<const bf16x8*>(&Al[buf][c][l][kt * 32 + q * 8]);
                #pragma unroll
                for (int mt = 0; mt < 4; ++mt)
                    acc[mt] = __builtin_amdgcn_mfma_f32_16x16x32_bf16(Afr[mt][kt], bfr, acc[mt], 0, 0, 0);
            }

            // epilogue: v = acc * exp(em) * pend   (pend = 2^-kap on first
            // unmasked step of the group, 1 afterwards)
            const int mk = mkv;
            float v[4][4]; float lmx = 0.0f;
            #pragma unroll
            for (int t = 0; t < 4; ++t) {
                if (PRE) {
                    v[t][0] = acc[t][0] * bf2f((ushort)(exv[t].x & 0xFFFF)) * pend;
                    v[t][1] = acc[t][1] * bf2f((ushort)(exv[t].x >> 16))    * pend;
                    v[t][2] = acc[t][2] * bf2f((ushort)(exv[t].y & 0xFFFF)) * pend;
                    v[t][3] = acc[t][3] * bf2f((ushort)(exv[t].y >> 16))    * pend;
                } else {
                    #pragma unroll
                    for (int r = 0; r < 4; ++r)
                        v[t][r] = acc[t][r] * exp2f(emv[t][r] * LOG2E) * pend;
                }
                #pragma unroll
                for (int r = 0; r < 4; ++r) lmx = fmaxf(lmx, v[t][r]);
            }

            if (mk) {
                #pragma unroll
                for (int t = 0; t < 4; ++t) {
                    int j0 = jq * 64 + t * 16 + q * 4;
                    uint2 w;
                    w.x = pack_bf16x2(v[t][0], v[t][1]);
                    w.y = pack_bf16x2(v[t][2], v[t][3]);
                    *reinterpret_cast<uint2*>(&Al[nb][c][l][j0]) = w;
                }
            } else {
                #pragma unroll
                for (int t = 0; t < 4; ++t) {
                    int j0 = jq * 64 + t * 16 + q * 4;
                    *reinterpret_cast<uint2*>(&Al[nb][c][l][j0]) =
                        *reinterpret_cast<const uint2*>(&Al[buf][c][l][j0]);
                }
            }
            // bookkeeping (per-lane predicated; batch-uniform across a wave's l)
            ls  += mk ? pk : 0;
            vml  = mk ? lmx : vml;
            pend = mk ? 1.0f : pend;
            pk   = mk ? 0 : pk;

            if (rn) {   // publish stored-alpha max for next group's kappa
                float m2 = fmaxf(vml, __shfl_xor(vml, 16));
                m2 = fmaxf(m2, __shfl_xor(m2, 32));
                if (q == 0) mxbuf[c][jq][l] = m2;
            }

            __syncthreads();
            buf = nb;
            #pragma unroll
            for (int t = 0; t < 4; ++t) { exv[t] = exn[t]; emv[t] = emn[t]; }
            mkv = mkn;
        }
    }

    // ---- final: res = ls + log2( sum_j alpha_stored[b][j] * exp(end[j]) )
    float part = 0.0f;
    #pragma unroll
    for (int kt = 0; kt < 8; ++kt) {
        int i0 = kt * 32 + q * 8;
        f32x4 ea = *reinterpret_cast<const f32x4*>(&endt[i0]);
        f32x4 eb = *reinterpret_cast<const f32x4*>(&endt[i0 + 4]);
        ushort4 a0 = *reinterpret_cast<const ushort4*>(&Al[buf][c][l][i0]);
        ushort4 a1 = *reinterpret_cast<const ushort4*>(&Al[buf][c][l][i0 + 4]);
        part += bf2f(a0.x) * exp2f(ea[0] * LOG2E);
        part += bf2f(a0.y) * exp2f(ea[1] * LOG2E);
        part += bf2f(a0.z) * exp2f(ea[2] * LOG2E);
        part += bf2f(a0.w) * exp2f(ea[3] * LOG2E);
        part += bf2f(a1.x) * exp2f(eb[0] * LOG2E);
        part += bf2f(a1.y) * exp2f(eb[1] * LOG2E);
        part += bf2f(a1.z) * exp2f(eb[2] * LOG2E);
        part += bf2f(a1.w) * exp2f(eb[3] * LOG2E);
    }
    part += __shfl_xor(part, 16);
    part += __shfl_xor(part, 32);

    if (jq == 0 && q == 0)
        res[scan * B + b] = (float)ls + log2f(part);
}

// ---------------- combine: out[b] = (partition - score) * ln2 ----------------
__global__ void combine(const float* __restrict__ res, float* __restrict__ out) {
    int b = threadIdx.x;  // 128
    out[b] = (res[b] - res[B + b]) * LN2;
}

extern "C" void kernel_launch(void* const* d_in, const int* in_sizes, int n_in,
                              void* d_out, int out_size, void* d_ws, size_t ws_size,
                              hipStream_t stream) {
    (void)in_sizes; (void)n_in; (void)out_size;
    const float* em = (const float*)d_in[0];
    const int*   mk = (const int*)d_in[1];
    const float* st = (const float*)d_in[2];
    const float* en = (const float*)d_in[3];
    const float* tr = (const float*)d_in[4];

    const size_t emx_bytes = (size_t)B * S * T * sizeof(ushort);   // 32 MiB
    ushort* emx = (ushort*)d_ws;
    float*  res = (float*)((char*)d_ws + emx_bytes);
    const bool pre = ws_size >= emx_bytes + 4096;

    if (pre) {
        prep_emx<<<(B * S * T) / (256 * 4), 256, 0, stream>>>(em, emx);
        crf_scan<true><<<8, 512, 0, stream>>>(em, emx, mk, st, en, tr, res);
    } else {
        res = (float*)d_ws;
        crf_scan<false><<<8, 512, 0, stream>>>(em, emx, mk, st, en, tr, res);
    }
    combine<<<1, B, 0, stream>>>(res, (float*)d_out);
}

// Round 5
// 637.968 us; speedup vs baseline: 1.6018x; 1.6018x over previous
//
#include <hip/hip_runtime.h>
#include <hip/hip_bf16.h>
#include <stdint.h>

#define LOG2E 1.44269504088896340736f
#define LN2   0.69314718055994530942f

typedef __attribute__((ext_vector_type(8))) __bf16 bf16x8;
typedef __attribute__((ext_vector_type(4))) float  f32x4;

static constexpr int B = 128, S = 512, T = 256;
static constexpr int LDP = T + 8;   // padded LDS row (bf16 elems)

static __device__ __forceinline__ uint pack_bf16x2(float a, float b) {
    __hip_bfloat162 h = __float22bfloat162_rn(make_float2(a, b));
    union { __hip_bfloat162 h; uint u; } cv; cv.h = h;
    return cv.u;
}
static __device__ __forceinline__ float bf2f(ushort u) {
    return __uint_as_float(((uint)u) << 16);
}

// ---------------- prep: Et[j][i] = bf16( exp(trans[i][j]) ) ----------------
__global__ void prep_Et(const float* __restrict__ trans, ushort* __restrict__ Et) {
    int j = blockIdx.x;    // 256
    int i = threadIdx.x;   // 256
    float e = exp2f(trans[i * T + j] * LOG2E);
    uint u = __float_as_uint(e);
    Et[j * T + i] = (ushort)((u + 0x7FFFu + ((u >> 16) & 1u)) >> 16);  // RTNE
}

// ---------------- prep: emx = bf16( exp(em) ), elementwise over B*S*T ----------------
__global__ void prep_emx(const float* __restrict__ em, ushort* __restrict__ emx) {
    size_t i4 = ((size_t)blockIdx.x * blockDim.x + threadIdx.x) * 4;
    f32x4 e = *reinterpret_cast<const f32x4*>(&em[i4]);
    uint2 w;
    w.x = pack_bf16x2(exp2f(e[0] * LOG2E), exp2f(e[1] * LOG2E));
    w.y = pack_bf16x2(exp2f(e[2] * LOG2E), exp2f(e[3] * LOG2E));
    *reinterpret_cast<uint2*>(&emx[i4]) = w;
}

// ---------------- main scan: one WG per (scan, batch-group of 16) ----------------
// R3 structure (16 WG x 256 thr, 1 chain, 4 waves) +
//  - group-of-4 delayed renormalization (exact power-of-2; validated R4):
//    kappa applied on the first unmasked step of each 4-group, stored alpha
//    otherwise unscaled (growth bounded well under fp32/bf16 range).
//  - em/mask loads batched per 8 steps, issued right after a barrier so the
//    per-step s_waitcnt vmcnt(0) barrier drains find them already complete.
// Both scans instruction-identical when mask==1 -> bitwise-identical results.
template<bool PRE>
__launch_bounds__(256, 1)
__global__ void crf_scan(const float* __restrict__ em,      // [B][S][T] fp32
                         const ushort* __restrict__ emx,    // [B][S][T] bf16 exp(em) (PRE)
                         const int* __restrict__ mask,      // [B][S] int32
                         const float* __restrict__ startt,  // [T]
                         const float* __restrict__ endt,    // [T]
                         const ushort* __restrict__ Et,     // [T][T] bf16, Et[j][i]=exp(trans[i][j])
                         float* __restrict__ res)           // [2][B] log2-domain results
{
    const int tid  = threadIdx.x;
    const int jq   = tid >> 6;          // wave: j-range [64*jq, 64*jq+64)
    const int lane = tid & 63;
    const int q    = lane >> 4;         // quad 0..3
    const int l    = lane & 15;         // local batch 0..15
    const int scan = blockIdx.x & 1;
    const int bg   = blockIdx.x >> 1;   // 0..7
    const int b    = bg * 16 + l;       // this lane's batch (MFMA N index)

    __shared__ __align__(16) ushort Al[2][16][LDP];   // alpha, bf16, double-buffered
    __shared__ __align__(16) float mx2[16][4];        // [batch][jq] stored-alpha max

    // ---- Et fragments (A-operand, step-invariant): 128 VGPRs/wave.
    bf16x8 Afr[4][8];
    #pragma unroll
    for (int mt = 0; mt < 4; ++mt) {
        int j = jq * 64 + mt * 16 + l;
        #pragma unroll
        for (int kt = 0; kt < 8; ++kt)
            Afr[mt][kt] = *reinterpret_cast<const bf16x8*>(&Et[j * T + kt * 32 + q * 8]);
    }

    const float*  emrow = em  + (size_t)b * S * T;
    const ushort* exrow = PRE ? emx + (size_t)b * S * T : nullptr;
    const int*    mrow  = mask + (size_t)b * S;

    int ls = 0;
    int buf = 0;

    // ---- init: alpha0 = exp(start + em[:,0]), normalized once
    {
        float v0[4][4]; float mx = 0.0f;
        #pragma unroll
        for (int t = 0; t < 4; ++t) {
            int j0 = jq * 64 + t * 16 + q * 4;
            f32x4 e4 = *reinterpret_cast<const f32x4*>(&emrow[j0]);
            f32x4 s4 = *reinterpret_cast<const f32x4*>(&startt[j0]);
            #pragma unroll
            for (int r = 0; r < 4; ++r) {
                v0[t][r] = exp2f((e4[r] + s4[r]) * LOG2E);
                mx = fmaxf(mx, v0[t][r]);
            }
        }
        mx = fmaxf(mx, __shfl_xor(mx, 16));
        mx = fmaxf(mx, __shfl_xor(mx, 32));
        if (q == 0) mx2[l][jq] = mx;
        __syncthreads();
        f32x4 m4 = *reinterpret_cast<const f32x4*>(&mx2[l][0]);
        float gmx = fmaxf(fmaxf(m4[0], m4[1]), fmaxf(m4[2], m4[3]));
        int e = (int)((__float_as_uint(gmx) >> 23) & 255u) - 127;
        float sc = __uint_as_float((uint)(127 - e) << 23);   // exact 2^-e
        ls = e;
        #pragma unroll
        for (int t = 0; t < 4; ++t) {
            int j0 = jq * 64 + t * 16 + q * 4;
            uint2 w;
            w.x = pack_bf16x2(v0[t][0] * sc, v0[t][1] * sc);
            w.y = pack_bf16x2(v0[t][2] * sc, v0[t][3] * sc);
            *reinterpret_cast<uint2*>(&Al[0][l][j0]) = w;
        }
        __syncthreads();
        if (q == 0) mx2[l][jq] = mx * sc;   // max of stored alpha0
        __syncthreads();
    }

    // ---- preload em/mask for group 0 (steps 1..8)
    uint2 exv[8][4]; int mks[8];
    #pragma unroll
    for (int u = 0; u < 8; ++u) {
        int s = 1 + u;
        #pragma unroll
        for (int t = 0; t < 4; ++t) {
            int j0 = jq * 64 + t * 16 + q * 4;
            if (PRE) exv[u][t] = *reinterpret_cast<const uint2*>(&exrow[(size_t)s * T + j0]);
        }
        mks[u] = scan ? mrow[s] : 1;
    }

    for (int p = 0; p < 64; ++p) {
        // ---- issue next group's loads now; they complete during step u=0
        uint2 exn[8][4]; int mkn[8];
        const int base = 9 + 8 * p;
        #pragma unroll
        for (int u = 0; u < 8; ++u) {
            int su  = base + u;
            int suc = su < S ? su : S - 1;
            #pragma unroll
            for (int t = 0; t < 4; ++t) {
                int j0 = jq * 64 + t * 16 + q * 4;
                if (PRE) exn[u][t] = *reinterpret_cast<const uint2*>(&exrow[(size_t)suc * T + j0]);
            }
            mkn[u] = (scan && su < S) ? mrow[su] : 1;
        }

        float pend = 1.0f, vml = 0.0f; int pk = 0;

        #pragma unroll
        for (int u = 0; u < 8; ++u) {
            const int s = 1 + 8 * p + u;
            if (s < S) {
                if ((u & 3) == 0) {   // renorm-group start: derive kappa
                    f32x4 m4 = *reinterpret_cast<const f32x4*>(&mx2[l][0]);
                    float gmx = fmaxf(fmaxf(m4[0], m4[1]), fmaxf(m4[2], m4[3]));
                    int kap = (int)((__float_as_uint(gmx) >> 23) & 255u) - 127;
                    pend = __uint_as_float((uint)(127 - kap) << 23);   // exact 2^-kap
                    pk   = kap;
                    vml  = gmx;
                }
                const int nb = buf ^ 1;

                // MFMA: P[j][b] = sum_i Et[j][i] * alpha_stored[b][i]
                f32x4 acc[4] = {f32x4{0,0,0,0}, f32x4{0,0,0,0}, f32x4{0,0,0,0}, f32x4{0,0,0,0}};
                #pragma unroll
                for (int kt = 0; kt < 8; ++kt) {
                    bf16x8 bfr = *reinterpret_cast<const bf16x8*>(&Al[buf][l][kt * 32 + q * 8]);
                    #pragma unroll
                    for (int mt = 0; mt < 4; ++mt)
                        acc[mt] = __builtin_amdgcn_mfma_f32_16x16x32_bf16(Afr[mt][kt], bfr, acc[mt], 0, 0, 0);
                }

                // epilogue: v = acc * exp(em) * pend
                const int mk = mks[u];
                float v[4][4]; float lmx = 0.0f;
                #pragma unroll
                for (int t = 0; t < 4; ++t) {
                    if (PRE) {
                        v[t][0] = acc[t][0] * bf2f((ushort)(exv[u][t].x & 0xFFFF)) * pend;
                        v[t][1] = acc[t][1] * bf2f((ushort)(exv[u][t].x >> 16))    * pend;
                        v[t][2] = acc[t][2] * bf2f((ushort)(exv[u][t].y & 0xFFFF)) * pend;
                        v[t][3] = acc[t][3] * bf2f((ushort)(exv[u][t].y >> 16))    * pend;
                    } else {
                        int j0 = jq * 64 + t * 16 + q * 4;
                        f32x4 e4 = *reinterpret_cast<const f32x4*>(&emrow[(size_t)s * T + j0]);
                        #pragma unroll
                        for (int r = 0; r < 4; ++r)
                            v[t][r] = acc[t][r] * exp2f(e4[r] * LOG2E) * pend;
                    }
                    #pragma unroll
                    for (int r = 0; r < 4; ++r) lmx = fmaxf(lmx, v[t][r]);
                }

                if (mk) {
                    #pragma unroll
                    for (int t = 0; t < 4; ++t) {
                        int j0 = jq * 64 + t * 16 + q * 4;
                        uint2 w;
                        w.x = pack_bf16x2(v[t][0], v[t][1]);
                        w.y = pack_bf16x2(v[t][2], v[t][3]);
                        *reinterpret_cast<uint2*>(&Al[nb][l][j0]) = w;
                    }
                } else {
                    #pragma unroll
                    for (int t = 0; t < 4; ++t) {
                        int j0 = jq * 64 + t * 16 + q * 4;
                        *reinterpret_cast<uint2*>(&Al[nb][l][j0]) =
                            *reinterpret_cast<const uint2*>(&Al[buf][l][j0]);
                    }
                }
                // bookkeeping (mask-generic; uniform across the wave per l)
                ls  += mk ? pk : 0;
                vml  = mk ? lmx : vml;
                pend = mk ? 1.0f : pend;
                pk   = mk ? 0 : pk;

                const bool rn = ((u & 3) == 3) || (s == S - 1);
                if (rn) {   // publish stored-alpha max for next renorm group
                    float m2 = fmaxf(vml, __shfl_xor(vml, 16));
                    m2 = fmaxf(m2, __shfl_xor(m2, 32));
                    if (q == 0) mx2[l][jq] = m2;
                }

                __syncthreads();
                buf = nb;
            }
        }

        #pragma unroll
        for (int u = 0; u < 8; ++u) {
            #pragma unroll
            for (int t = 0; t < 4; ++t) exv[u][t] = exn[u][t];
            mks[u] = mkn[u];
        }
    }

    // ---- final: res = ls + log2( sum_j alpha_stored[b][j] * exp(end[j]) )
    float part = 0.0f;
    #pragma unroll
    for (int kt = 0; kt < 8; ++kt) {
        int i0 = kt * 32 + q * 8;
        f32x4 ea = *reinterpret_cast<const f32x4*>(&endt[i0]);
        f32x4 eb = *reinterpret_cast<const f32x4*>(&endt[i0 + 4]);
        ushort4 a0 = *reinterpret_cast<const ushort4*>(&Al[buf][l][i0]);
        ushort4 a1 = *reinterpret_cast<const ushort4*>(&Al[buf][l][i0 + 4]);
        part += bf2f(a0.x) * exp2f(ea[0] * LOG2E);
        part += bf2f(a0.y) * exp2f(ea[1] * LOG2E);
        part += bf2f(a0.z) * exp2f(ea[2] * LOG2E);
        part += bf2f(a0.w) * exp2f(ea[3] * LOG2E);
        part += bf2f(a1.x) * exp2f(eb[0] * LOG2E);
        part += bf2f(a1.y) * exp2f(eb[1] * LOG2E);
        part += bf2f(a1.z) * exp2f(eb[2] * LOG2E);
        part += bf2f(a1.w) * exp2f(eb[3] * LOG2E);
    }
    part += __shfl_xor(part, 16);
    part += __shfl_xor(part, 32);

    if (jq == 0 && q == 0)
        res[scan * B + b] = (float)ls + log2f(part);
}

// ---------------- combine: out[b] = (partition - score) * ln2 ----------------
__global__ void combine(const float* __restrict__ res, float* __restrict__ out) {
    int b = threadIdx.x;  // 128
    out[b] = (res[b] - res[B + b]) * LN2;
}

extern "C" void kernel_launch(void* const* d_in, const int* in_sizes, int n_in,
                              void* d_out, int out_size, void* d_ws, size_t ws_size,
                              hipStream_t stream) {
    (void)in_sizes; (void)n_in; (void)out_size;
    const float* em = (const float*)d_in[0];
    const int*   mk = (const int*)d_in[1];
    const float* st = (const float*)d_in[2];
    const float* en = (const float*)d_in[3];
    const float* tr = (const float*)d_in[4];

    const size_t emx_bytes = (size_t)B * S * T * sizeof(ushort);   // 32 MiB
    ushort* emx = (ushort*)d_ws;
    ushort* Et  = (ushort*)((char*)d_ws + emx_bytes);              // 128 KiB
    float*  res = (float*)((char*)d_ws + emx_bytes + (T * T * sizeof(ushort)));
    const bool pre = ws_size >= emx_bytes + T * T * sizeof(ushort) + 4096;

    if (pre) {
        prep_Et<<<T, T, 0, stream>>>(tr, Et);
        prep_emx<<<(B * S * T) / (256 * 4), 256, 0, stream>>>(em, emx);
        crf_scan<true><<<16, 256, 0, stream>>>(em, emx, mk, st, en, Et, res);
    } else {
        Et  = (ushort*)d_ws;
        res = (float*)((char*)d_ws + (T * T * sizeof(ushort)));
        prep_Et<<<T, T, 0, stream>>>(tr, Et);
        crf_scan<false><<<16, 256, 0, stream>>>(em, emx, mk, st, en, Et, res);
    }
    combine<<<1, B, 0, stream>>>(res, (float*)d_out);
}